// Round 2
// baseline (140.632 us; speedup 1.0000x reference)
//
#include <hip/hip_runtime.h>

// [T+1, B] = [1024, 4096] fp32, time-major.
#define T      1023
#define B      4096
#define B4     1024      // B / 4 (float4 lanes)
#define CHUNK  16
#define NCHUNK 64        // chunk c covers t in [16c, min(16c+16, 1023))

#define GAMMA     0.99f
#define TD_LAMBDA 0.95f

// Per-component GAE affine step: adv = nl*(delta + wd*adv_next)
// Composed form per chunk: adv[s] = A + Bf*adv[e]
#define COMPOSE_STEP(comp)                                              \
    {                                                                   \
        float d1    = d.comp * GAMMA;                                   \
        float delta = r.comp + d1 * tvn.comp - tvt.comp;                \
        float wd    = d1 * TD_LAMBDA;                                   \
        float nl    = (stt.comp == 2) ? 0.f : 1.f;                      \
        float a     = nl * delta;                                       \
        float bb    = nl * wd;                                          \
        A.comp  = fmaf(bb, A.comp, a);                                  \
        Bf.comp = bb * Bf.comp;                                         \
        tvn.comp = tvt.comp;                                            \
    }

#define REPLAY_STEP(comp)                                               \
    {                                                                   \
        float d1    = d.comp * GAMMA;                                   \
        float delta = r.comp + d1 * tvn.comp - tvt.comp;                \
        float wd    = d1 * TD_LAMBDA;                                   \
        float nl    = (stt.comp == 2) ? 0.f : 1.f;                      \
        adv.comp    = nl * fmaf(wd, adv.comp, delta);                   \
        float td    = adv.comp + tvt.comp - val.comp;                   \
        o.comp      = td * td;                                          \
        tvn.comp    = tvt.comp;                                         \
    }

// Phase 1: per (chunk, 4-column group), compose the chunk's affine steps.
__global__ __launch_bounds__(256) void k_compose(
    const float4* __restrict__ tv, const float4* __restrict__ rew,
    const int4* __restrict__ st, const float4* __restrict__ disc,
    float4* __restrict__ Ac, float4* __restrict__ Bc)
{
    int tid = blockIdx.x * blockDim.x + threadIdx.x;  // 0 .. 64*1024-1
    int j = tid & (B4 - 1);
    int c = tid >> 10;
    int s = c * CHUNK;
    int e = min(s + CHUNK, T);

    float4 A  = make_float4(0.f, 0.f, 0.f, 0.f);
    float4 Bf = make_float4(1.f, 1.f, 1.f, 1.f);
    float4 tvn = tv[e * B4 + j];
    for (int t = e - 1; t >= s; --t) {
        int i0 = t * B4 + j;
        int i1 = i0 + B4;
        float4 d   = disc[i1];
        float4 r   = rew[i1];
        int4   stt = st[i0];
        float4 tvt = tv[i0];
        COMPOSE_STEP(x) COMPOSE_STEP(y) COMPOSE_STEP(z) COMPOSE_STEP(w)
    }
    Ac[tid] = A;     // layout [c][j]
    Bc[tid] = Bf;
}

// Phase 2: sequential scan over the 64 chunk boundaries, per 4-column group.
// R[c][j] = adv entering chunk c from the right (adv at t = chunk_end(c)).
__global__ __launch_bounds__(256) void k_scan(
    const float4* __restrict__ Ac, const float4* __restrict__ Bc,
    float4* __restrict__ R)
{
    int j = blockIdx.x * blockDim.x + threadIdx.x;   // 0..B4-1
    float4 adv = make_float4(0.f, 0.f, 0.f, 0.f);
    for (int c = NCHUNK - 1; c >= 0; --c) {
        int i = c * B4 + j;
        R[i] = adv;
        float4 a = Ac[i], b = Bc[i];
        adv.x = fmaf(b.x, adv.x, a.x);
        adv.y = fmaf(b.y, adv.y, a.y);
        adv.z = fmaf(b.z, adv.z, a.z);
        adv.w = fmaf(b.w, adv.w, a.w);
    }
}

// Phase 3: replay each chunk with its known right-boundary adv; emit loss.
__global__ __launch_bounds__(256) void k_replay(
    const float4* __restrict__ value, const float4* __restrict__ tv,
    const float4* __restrict__ rew, const int4* __restrict__ st,
    const float4* __restrict__ disc, const float4* __restrict__ R,
    float4* __restrict__ out)
{
    int tid = blockIdx.x * blockDim.x + threadIdx.x;
    int j = tid & (B4 - 1);
    int c = tid >> 10;
    int s = c * CHUNK;
    int e = min(s + CHUNK, T);

    float4 adv = R[tid];
    float4 tvn = tv[e * B4 + j];
    if (c == NCHUNK - 1) {
        // tensor_extend_zero: last output row is zeros (d_out is re-poisoned).
        out[T * B4 + j] = make_float4(0.f, 0.f, 0.f, 0.f);
    }
    for (int t = e - 1; t >= s; --t) {
        int i0 = t * B4 + j;
        int i1 = i0 + B4;
        float4 d   = disc[i1];
        float4 r   = rew[i1];
        int4   stt = st[i0];
        float4 tvt = tv[i0];
        float4 val = value[i0];
        float4 o;
        REPLAY_STEP(x) REPLAY_STEP(y) REPLAY_STEP(z) REPLAY_STEP(w)
        out[i0] = o;
    }
}

extern "C" void kernel_launch(void* const* d_in, const int* in_sizes, int n_in,
                              void* d_out, int out_size, void* d_ws, size_t ws_size,
                              hipStream_t stream) {
    // setup_inputs order: value, target_value, reward, step_type, discount
    const float4* value = (const float4*)d_in[0];
    const float4* tv    = (const float4*)d_in[1];
    const float4* rew   = (const float4*)d_in[2];
    const int4*   st    = (const int4*)d_in[3];
    const float4* disc  = (const float4*)d_in[4];
    float4* out = (float4*)d_out;

    // Workspace: 3 arrays of NCHUNK*B floats = 3 MiB total (ws is 0xAA-poisoned;
    // every element we read is written first by k_compose/k_scan).
    float4* Ac = (float4*)d_ws;
    float4* Bc = Ac + (size_t)NCHUNK * B4;
    float4* R  = Bc + (size_t)NCHUNK * B4;

    k_compose<<<(NCHUNK * B4) / 256, 256, 0, stream>>>(tv, rew, st, disc, Ac, Bc);
    k_scan<<<B4 / 256, 256, 0, stream>>>(Ac, Bc, R);
    k_replay<<<(NCHUNK * B4) / 256, 256, 0, stream>>>(value, tv, rew, st, disc, R, out);
}

// Round 4
// 134.283 us; speedup vs baseline: 1.0473x; 1.0473x over previous
//
#include <hip/hip_runtime.h>

// [T+1, B] = [1024, 4096] fp32, time-major.
#define T      1023
#define B      4096
#define B4     1024      // B / 4 (float4 column groups)
#define CHUNK  16
#define NCHUNK 64        // chunk c covers t in [16c, min(16c+16, 1023))

#define GAMMA     0.99f
#define TD_LAMBDA 0.95f

// GAE step: adv[t] = nl_t * (delta_t + wd_t * adv[t+1])  ==  a_t + b_t*adv[t+1]
// Chunk composition: adv[s] = A + Bf * adv[e].

#define COMPOSE_STEP(comp)                                              \
    {                                                                   \
        float d1    = d.comp * GAMMA;                                   \
        float delta = r.comp + d1 * tvn.comp - tvt.comp;                \
        float nl    = (stt.comp == 2) ? 0.f : 1.f;                      \
        float a     = nl * delta;                                       \
        float bb    = nl * (d1 * TD_LAMBDA);                            \
        A.comp  = fmaf(bb, A.comp, a);                                  \
        Bf.comp = bb * Bf.comp;                                         \
        tvn.comp = tvt.comp;                                            \
    }

#define REPLAY_STEP(comp)                                               \
    {                                                                   \
        float d1    = d.comp * GAMMA;                                   \
        float delta = r.comp + d1 * tvn.comp - tvt.comp;                \
        float nl    = (stt.comp == 2) ? 0.f : 1.f;                      \
        adv.comp    = nl * fmaf(d1 * TD_LAMBDA, adv.comp, delta);       \
        float td    = adv.comp + tvt.comp - val.comp;                   \
        o.comp      = td * td;                                          \
        tvn.comp    = tvt.comp;                                         \
    }

// K1: per (chunk, 4-col group) compose the chunk's affine map into (Ac, Bc).
__global__ __launch_bounds__(256) void k_compose(
    const float4* __restrict__ tv, const float4* __restrict__ rew,
    const int4* __restrict__ st, const float4* __restrict__ disc,
    float4* __restrict__ Ac, float4* __restrict__ Bc)
{
    const int tid = blockIdx.x * 256 + threadIdx.x;   // 0 .. NCHUNK*B4-1
    const int j = tid & (B4 - 1);
    const int c = tid >> 10;
    const int s = c * CHUNK;
    const int e = min(s + CHUNK, T);

    float4 A  = make_float4(0.f, 0.f, 0.f, 0.f);
    float4 Bf = make_float4(1.f, 1.f, 1.f, 1.f);
    float4 tvn = tv[e * B4 + j];
    #pragma unroll
    for (int k = CHUNK - 1; k >= 0; --k) {
        const int t = s + k;
        if (t < T) {                                  // false only for (c=63,k=15)
            const int i0 = t * B4 + j;
            const int i1 = i0 + B4;
            const float4 d   = disc[i1];
            const float4 r   = rew[i1];
            const int4   stt = st[i0];
            const float4 tvt = tv[i0];
            COMPOSE_STEP(x) COMPOSE_STEP(y) COMPOSE_STEP(z) COMPOSE_STEP(w)
        }
    }
    Ac[tid] = A;
    Bc[tid] = Bf;
}

// K2: per (chunk, 4-col group): lookback-compose chunks c+1..63 to get the
// right-boundary adv, then replay the chunk from the inputs and emit loss.
__global__ __launch_bounds__(256) void k_replay(
    const float4* __restrict__ value, const float4* __restrict__ tv,
    const float4* __restrict__ rew, const int4* __restrict__ st,
    const float4* __restrict__ disc,
    const float4* __restrict__ Ac, const float4* __restrict__ Bc,
    float4* __restrict__ out)
{
    const int tid = blockIdx.x * 256 + threadIdx.x;
    const int j = tid & (B4 - 1);
    const int c = tid >> 10;
    const int s = c * CHUNK;
    const int e = min(s + CHUNK, T);

    // ---- lookback: adv entering chunk c from the right ----
    // adv_e(c) = f_{c+1}(f_{c+2}(...f_{63}(0))), applied innermost-first.
    float4 adv = make_float4(0.f, 0.f, 0.f, 0.f);
    int cc = NCHUNK - 1;
    while (cc > c) {                                   // wave-uniform trip count
        float4 Ab[8], Bb[8];
        #pragma unroll
        for (int k = 0; k < 8; ++k) {                  // batch loads: pay latency once per 8
            const int ccc = cc - k;
            const int i = (ccc > c ? ccc : cc) * B4 + j;   // clamp to a valid addr
            Ab[k] = Ac[i];
            Bb[k] = Bc[i];
            if (ccc <= c) {                            // identity for overrun slots
                Ab[k] = make_float4(0.f, 0.f, 0.f, 0.f);
                Bb[k] = make_float4(1.f, 1.f, 1.f, 1.f);
            }
        }
        #pragma unroll
        for (int k = 0; k < 8; ++k) {
            adv.x = fmaf(Bb[k].x, adv.x, Ab[k].x);
            adv.y = fmaf(Bb[k].y, adv.y, Ab[k].y);
            adv.z = fmaf(Bb[k].z, adv.z, Ab[k].z);
            adv.w = fmaf(Bb[k].w, adv.w, Ab[k].w);
        }
        cc -= 8;
    }

    // ---- replay ----
    float4 tvn = tv[e * B4 + j];
    if (c == NCHUNK - 1)                               // tensor_extend_zero row
        out[T * B4 + j] = make_float4(0.f, 0.f, 0.f, 0.f);
    #pragma unroll
    for (int k = CHUNK - 1; k >= 0; --k) {
        const int t = s + k;
        if (t < T) {
            const int i0 = t * B4 + j;
            const int i1 = i0 + B4;
            const float4 d   = disc[i1];
            const float4 r   = rew[i1];
            const int4   stt = st[i0];
            const float4 tvt = tv[i0];
            const float4 val = value[i0];
            float4 o;
            REPLAY_STEP(x) REPLAY_STEP(y) REPLAY_STEP(z) REPLAY_STEP(w)
            out[i0] = o;
        }
    }
}

extern "C" void kernel_launch(void* const* d_in, const int* in_sizes, int n_in,
                              void* d_out, int out_size, void* d_ws, size_t ws_size,
                              hipStream_t stream) {
    // setup_inputs order: value, target_value, reward, step_type, discount
    const float4* value = (const float4*)d_in[0];
    const float4* tv    = (const float4*)d_in[1];
    const float4* rew   = (const float4*)d_in[2];
    const int4*   st    = (const int4*)d_in[3];
    const float4* disc  = (const float4*)d_in[4];
    float4* out = (float4*)d_out;

    float4* Ac = (float4*)d_ws;                  // [NCHUNK][B4] float4 — 1 MiB
    float4* Bc = Ac + (size_t)NCHUNK * B4;       // 1 MiB

    k_compose<<<(NCHUNK * B4) / 256, 256, 0, stream>>>(tv, rew, st, disc, Ac, Bc);
    k_replay<<<(NCHUNK * B4) / 256, 256, 0, stream>>>(value, tv, rew, st, disc,
                                                      Ac, Bc, out);
}